// Round 8
// baseline (15992.006 us; speedup 1.0000x reference)
//
#include <hip/hip_runtime.h>

typedef unsigned short u16;
typedef unsigned int   u32;
typedef _Float16 f16;
typedef f16   f16x2 __attribute__((ext_vector_type(2)));
typedef f16   f16x8 __attribute__((ext_vector_type(8)));
typedef float f32x4 __attribute__((ext_vector_type(4)));
typedef u32   u32x4 __attribute__((ext_vector_type(4)));

#define B_  64
#define L_  384
#define CS  512   // SRC_DIM
#define H_  512
#define E_  256
#define NC  250
#define T_  127
#define MSHIFT 20.0f   // fixed softmax shift; |logit| <= ||wscore||_1 ~ 20.4 << 88
#define NBLK 160       // persistent grid

__device__ __forceinline__ float h2f(u16 u){ f16 h; __builtin_memcpy(&h,&u,2); return (float)h; }
__device__ __forceinline__ u16  f2h(float f){ f16 h=(f16)f; u16 u; __builtin_memcpy(&u,&h,2); return u; }
__device__ __forceinline__ float wredsum(float v){
#pragma unroll
  for (int o=32;o>0;o>>=1) v += __shfl_down(v, o, 64);
  return v;
}
__device__ __forceinline__ float tanh_f(float x){
  x = fminf(fmaxf(x, -15.f), 15.f);
  float e = __expf(2.f*x);
  return (e-1.f)/(e+1.f);
}
__device__ __forceinline__ float sigm_f(float x){
  x = fminf(fmaxf(x, -30.f), 30.f);
  return 1.f/(1.f+__expf(-x));
}
__device__ __forceinline__ float dot2f(u32 a, u32 b, float c){
  f16x2 x, y; __builtin_memcpy(&x,&a,4); __builtin_memcpy(&y,&b,4);
#if __has_builtin(__builtin_amdgcn_fdot2)
  return __builtin_amdgcn_fdot2(x, y, c, false);
#else
  return c + (float)x[0]*(float)y[0] + (float)x[1]*(float)y[1];
#endif
}

// ---------------- one-time converters / packers (all verified in prior rounds) -------------
__global__ __launch_bounds__(256) void k_cvt(const float* __restrict__ in, f16* __restrict__ o, int n){
  int i = blockIdx.x*256 + threadIdx.x;
  if (i < n) o[i] = (f16)in[i];
}

__global__ __launch_bounds__(256) void k_packwhq(const float* __restrict__ Wh, u32* __restrict__ Wq){
  int i = blockIdx.x*256 + threadIdx.x;   // over 64*512*4
  if (i < 64*512*4){
    int kq = i >> 11, n = (i >> 2) & 511, e = i & 3;
    int k = kq*8 + e*2;
    u32 lo = f2h(Wh[(size_t)n*512 + k]);
    u32 hi = f2h(Wh[(size_t)n*512 + k + 1]);
    Wq[i] = lo | (hi<<16);
  }
}

// ctx-part gates weights: row pc = hd*4+g <-> orig r = g*512+hd; k in [0,512)
__global__ __launch_bounds__(256) void k_packwcp(const float* __restrict__ Wih, f16* __restrict__ Wcp){
  int i = blockIdx.x*256 + threadIdx.x;   // over 2048*512
  if (i < 2048*512){
    int pc = i >> 9, k = i & 511;
    int r = (pc&3)*512 + (pc>>2);
    Wcp[i] = (f16)Wih[(size_t)r*768 + k];
  }
}

// [emb|h]-part gates weights. WgP[pc][k'] with r=(pc&3)*512+(pc>>2).
__global__ __launch_bounds__(256) void k_packwgp2(const float* __restrict__ Wih,
    const float* __restrict__ Whh, const float* __restrict__ bih, const float* __restrict__ bhh,
    f16* __restrict__ WgP, float* __restrict__ bias_g){
  int i = blockIdx.x*256 + threadIdx.x;   // over 2048*768
  if (i < 2048*768){
    int pc = i / 768, k = i - pc*768;
    int r = (pc&3)*512 + (pc>>2);
    float v = (k < 256) ? Wih[(size_t)r*768 + 512 + k] : Whh[(size_t)r*512 + (k-256)];
    WgP[i] = (f16)v;
    if (k == 0) bias_g[pc] = bih[r] + bhh[r];
  }
}

__global__ __launch_bounds__(256) void k_emb(const int* __restrict__ text,
    const float* __restrict__ embt, f16* __restrict__ embseq){
  int i = blockIdx.x*256 + threadIdx.x;
  if (i < B_*T_*E_){
    int bt = i >> 8, col = i & 255;
    int tok = text[bt];
    embseq[i] = (f16)embt[(size_t)tok*E_ + col];
  }
}

// ---------------- GEMM1 (MFMA, verified): C = A(f32)[M,512] @ Wn(f16)[N,512]^T -> f16[M,N]
__global__ __launch_bounds__(256) void k_sf_mfma(
    const float* __restrict__ A, const f16* __restrict__ Wn, u16* __restrict__ Cd, int N)
{
  int w = threadIdx.x >> 6, lane = threadIdx.x & 63;
  int quad = lane >> 4, l16 = lane & 15;
  int m0 = blockIdx.x * 64;
  int nb = blockIdx.y * 256 + w * 64;
  const float* ap0 = A  + (size_t)(m0 + l16)*512 + quad*8;
  const f16*   bp0 = Wn + (size_t)(nb + l16)*512 + quad*8;
  f32x4 acc[4][4] = {};
  for (int k0=0; k0<512; k0+=32){
    f16x8 bfr[4];
#pragma unroll
    for (int nt=0; nt<4; nt++)
      bfr[nt] = *(const f16x8*)(bp0 + (size_t)nt*16*512 + k0);
#pragma unroll
    for (int f=0; f<4; f++){
      const float* ap = ap0 + (size_t)f*16*512 + k0;
      float4 a0 = *(const float4*)ap;
      float4 a1 = *(const float4*)(ap+4);
      f16x8 afr = { (f16)a0.x,(f16)a0.y,(f16)a0.z,(f16)a0.w,
                    (f16)a1.x,(f16)a1.y,(f16)a1.z,(f16)a1.w };
#pragma unroll
      for (int nt=0; nt<4; nt++)
        acc[f][nt] = __builtin_amdgcn_mfma_f32_16x16x32_f16(afr, bfr[nt], acc[f][nt], 0,0,0);
    }
  }
#pragma unroll
  for (int f=0; f<4; f++)
#pragma unroll
    for (int nt=0; nt<4; nt++)
#pragma unroll
      for (int r=0; r<4; r++){
        int m = m0 + f*16 + quad*4 + r;
        int n = nb + nt*16 + l16;
        Cd[(size_t)m*N + n] = f2h(acc[f][nt][r]);
      }
}

// ---------------- probs GEMM (MFMA, verified r6/r7)
__global__ __launch_bounds__(256) void k_probs_mfma(
    const u16* __restrict__ A, const f16* __restrict__ Wn,
    const float* __restrict__ bias, float* __restrict__ Cd)
{
  int w = threadIdx.x >> 6, lane = threadIdx.x & 63;
  int quad = lane >> 4, l16 = lane & 15;
  int m0 = blockIdx.x * 64;
  int nb = w * 64;
  const f16* ap0 = (const f16*)A + (size_t)(m0 + l16)*512 + quad*8;
  const f16* bp0 = Wn + (size_t)(nb + l16)*512 + quad*8;
  f32x4 acc[4][4] = {};
  for (int k0=0; k0<512; k0+=32){
    f16x8 bfr[4];
#pragma unroll
    for (int nt=0; nt<4; nt++)
      bfr[nt] = *(const f16x8*)(bp0 + (size_t)nt*16*512 + k0);
#pragma unroll
    for (int f=0; f<4; f++){
      f16x8 afr = *(const f16x8*)(ap0 + (size_t)f*16*512 + k0);
#pragma unroll
      for (int nt=0; nt<4; nt++)
        acc[f][nt] = __builtin_amdgcn_mfma_f32_16x16x32_f16(afr, bfr[nt], acc[f][nt], 0,0,0);
    }
  }
#pragma unroll
  for (int f=0; f<4; f++)
#pragma unroll
    for (int nt=0; nt<4; nt++)
#pragma unroll
      for (int r=0; r<4; r++){
        int m = m0 + f*16 + quad*4 + r;
        int n = nb + nt*16 + l16;
        if (n < NC) Cd[(size_t)m*NC + n] = acc[f][nt][r] + bias[n];
      }
}

// ---------------- persistent decode loop with store-based grid barrier ----------------
// 160 blocks x 512 thr, 1 block/CU (LDS 84KB). 2 barriers/step.
// Phase A: blocks 0..127 att (b=bid>>1, q=bid&1, 192 l-rows each);
//          blocks 128..159 gpart MFMA (n-chunk of 64).
// Phase B: blocks 0..31 combine ctx + ctx-gates MFMA + LSTM cell.
__global__ __launch_bounds__(512, 1) void k_loop(
    const u32* __restrict__ WhQ, const u16* __restrict__ sf,
    const f16* __restrict__ src16, const float* __restrict__ bh2h,
    const float* __restrict__ wsc,
    const f16* __restrict__ WgP, const float* __restrict__ bias_g,
    const f16* __restrict__ Wcp, const f16* __restrict__ embseq,
    f16* __restrict__ hbuf, float* __restrict__ ctxp, float* __restrict__ denp,
    float* __restrict__ gpart, float* __restrict__ cbuf, u16* __restrict__ hs,
    u32* __restrict__ slots, u32* __restrict__ gen)
{
  const int tid = threadIdx.x;
  const int bid = blockIdx.x;
  const int wid = tid >> 6, lane = tid & 63;
  const int quad = lane >> 4, l16 = lane & 15;

  __shared__ __align__(16) union SM {
    struct { u32 h2[256]; float proj[512]; float e[192]; float cp[8][512]; } a;
    struct { f16 ctx[64][520]; float g[4][64][17]; float inv[64]; } b;
  } sm;

  u32 g = 0;

  for (int t=0; t<T_; ++t){
    // ================= Phase A =================
    if (bid < 128){
      const int b = bid >> 1;
      const int q = bid & 1;
      if (tid < 256) sm.a.h2[tid] = ((const u32*)(hbuf + (size_t)b*512))[tid];
      __syncthreads();
      // proj[n=tid]: 64 iters of u32x4 over WhQ (verified r4)
      {
        const u32* wp = WhQ + ((size_t)tid << 2);
        const u32x4* hp = (const u32x4*)sm.a.h2;
        float a0=0.f, a1=0.f, a2=0.f, a3=0.f;
#pragma unroll 8
        for (int kq=0; kq<64; kq++){
          u32x4 wq = *(const u32x4*)(wp + ((size_t)kq << 11));
          u32x4 hq = hp[kq];
          a0 = dot2f(wq.x, hq.x, a0);
          a1 = dot2f(wq.y, hq.y, a1);
          a2 = dot2f(wq.z, hq.z, a2);
          a3 = dot2f(wq.w, hq.w, a3);
        }
        sm.a.proj[tid] = (a0+a1) + (a2+a3) + bh2h[tid];
      }
      __syncthreads();
      // logit rows + fixed-shift exp (verified r4/r6); 8 waves x 24 rows
      {
        float pv[8], wv[8];
#pragma unroll
        for (int j=0;j<8;j++){ pv[j]=sm.a.proj[lane*8+j]; wv[j]=wsc[lane*8+j]; }
        const int l0 = q*192 + wid*24;
        const f16* sp0 = (const f16*)sf + (((size_t)(b*L_ + l0)) << 9) + lane*8;
#pragma unroll 4
        for (int i=0;i<24;i++){
          f16x8 s = *(const f16x8*)(sp0 + ((size_t)i << 9));
          float v;
          v  = tanh_f((float)s[0]+pv[0])*wv[0];
          v += tanh_f((float)s[1]+pv[1])*wv[1];
          v += tanh_f((float)s[2]+pv[2])*wv[2];
          v += tanh_f((float)s[3]+pv[3])*wv[3];
          v += tanh_f((float)s[4]+pv[4])*wv[4];
          v += tanh_f((float)s[5]+pv[5])*wv[5];
          v += tanh_f((float)s[6]+pv[6])*wv[6];
          v += tanh_f((float)s[7]+pv[7])*wv[7];
          v = wredsum(v);
          if (lane == 0) sm.a.e[wid*24 + i] = __expf(v - MSHIFT);
        }
      }
      __syncthreads();
      // den partial (wave 0): sum of 192 e's
      if (wid == 0){
        float v = sm.a.e[lane] + sm.a.e[64+lane] + sm.a.e[128+lane];
        v = wredsum(v);
        if (lane == 0) denp[q*64 + b] = v;
      }
      // partial ctx': wave w rows 24w..24w+23 (coalesced 1KB rows)
      {
        float acc[8] = {0.f,0.f,0.f,0.f,0.f,0.f,0.f,0.f};
        const f16* sp0 = src16 + (((size_t)(b*L_ + q*192 + wid*24)) << 9) + lane*8;
        const float* alp = sm.a.e + wid*24;
#pragma unroll 4
        for (int i=0;i<24;i++){
          f16x8 v = *(const f16x8*)(sp0 + ((size_t)i << 9));
          float al = alp[i];
#pragma unroll
          for (int e=0;e<8;e++) acc[e] += al*(float)v[e];
        }
#pragma unroll
        for (int e=0;e<8;e++) sm.a.cp[wid][lane*8+e] = acc[e];
      }
      __syncthreads();
      if (tid < 256){
        int c0 = tid*2;
        float v0 = (((sm.a.cp[0][c0]+sm.a.cp[1][c0])+(sm.a.cp[2][c0]+sm.a.cp[3][c0]))
                  + ((sm.a.cp[4][c0]+sm.a.cp[5][c0])+(sm.a.cp[6][c0]+sm.a.cp[7][c0])));
        int c1 = c0+1;
        float v1 = (((sm.a.cp[0][c1]+sm.a.cp[1][c1])+(sm.a.cp[2][c1]+sm.a.cp[3][c1]))
                  + ((sm.a.cp[4][c1]+sm.a.cp[5][c1])+(sm.a.cp[6][c1]+sm.a.cp[7][c1])));
        float2 o; o.x = v0; o.y = v1;
        *(float2*)(ctxp + (((size_t)(q*64 + b)) << 9) + c0) = o;
      }
    } else {
      // gpart blocks: c = bid-128 in [0,32); n-chunk of 64. (adapted from verified r6)
      const int c = bid - 128;
      const int wrow = wid & 3, half = wid >> 2;
      const int n = c*64 + wrow*16 + l16;
      const f16* bp = WgP + (size_t)n*768 + quad*8;
      f32x4 acc[2] = {};
      for (int k0=0; k0<256; k0+=32){
        f16x8 bfr = *(const f16x8*)(bp + k0);
#pragma unroll
        for (int ff=0; ff<2; ff++){
          int br = (half*2+ff)*16 + l16;
          f16x8 afr = *(const f16x8*)(embseq + (((size_t)(br*T_ + t)) << 8) + quad*8 + k0);
          acc[ff] = __builtin_amdgcn_mfma_f32_16x16x32_f16(afr, bfr, acc[ff], 0,0,0);
        }
      }
      for (int k0=0; k0<512; k0+=32){
        f16x8 bfr = *(const f16x8*)(bp + 256 + k0);
#pragma unroll
        for (int ff=0; ff<2; ff++){
          int br = (half*2+ff)*16 + l16;
          f16x8 afr = *(const f16x8*)(hbuf + (size_t)br*512 + quad*8 + k0);
          acc[ff] = __builtin_amdgcn_mfma_f32_16x16x32_f16(afr, bfr, acc[ff], 0,0,0);
        }
      }
      float bias = bias_g[n];
#pragma unroll
      for (int ff=0; ff<2; ff++)
#pragma unroll
        for (int r=0; r<4; r++){
          int b2 = (half*2+ff)*16 + quad*4 + r;
          gpart[((size_t)b2 << 11) + n] = acc[ff][r] + bias;
        }
    }

    // ---------- grid barrier 1 ----------
    ++g;
    __threadfence();
    __syncthreads();
    if (bid == 0){
      if (tid >= 1 && tid < NBLK)
        while (__hip_atomic_load(&slots[tid], __ATOMIC_RELAXED, __HIP_MEMORY_SCOPE_AGENT) < g)
          __builtin_amdgcn_s_sleep(1);
      __syncthreads();
      if (tid == 0) __hip_atomic_store(gen, g, __ATOMIC_RELAXED, __HIP_MEMORY_SCOPE_AGENT);
    } else {
      if (tid == 0){
        __hip_atomic_store(&slots[bid], g, __ATOMIC_RELAXED, __HIP_MEMORY_SCOPE_AGENT);
        while (__hip_atomic_load(gen, __ATOMIC_RELAXED, __HIP_MEMORY_SCOPE_AGENT) < g)
          __builtin_amdgcn_s_sleep(1);
      }
      __syncthreads();
    }
    __threadfence();

    // ================= Phase B (blocks 0..31) =================
    if (bid < 32){
      const int j2 = bid;
      if (tid < 64)
        sm.b.inv[tid] = 1.f/(denp[tid] + denp[64+tid]);
      __syncthreads();
      // combine 2 ctx' slices -> normalized f16 ctx (8192 float4 / 512 thr = 16 iters)
#pragma unroll 4
      for (int i=0;i<16;i++){
        int flat = tid + i*512;
        int b = flat >> 7, c4 = flat & 127;
        const float* base = ctxp + ((size_t)b << 9) + (c4 << 2);
        float4 v0 = *(const float4*)(base);
        float4 v1 = *(const float4*)(base + (64<<9));
        float inv = sm.b.inv[b];
        ushort4 o;
        o.x = f2h((v0.x+v1.x)*inv);
        o.y = f2h((v0.y+v1.y)*inv);
        o.z = f2h((v0.z+v1.z)*inv);
        o.w = f2h((v0.w+v1.w)*inv);
        *(ushort4*)&sm.b.ctx[b][c4*4] = o;
      }
      __syncthreads();
      // ctx-gates MFMA (verified r7): wave (wrow, half)
      {
        const int wrow = wid & 3, half = wid >> 2;
        const f16* bp = Wcp + (size_t)(j2*64 + wrow*16 + l16)*512 + quad*8;
        f32x4 acc[2] = {};
        for (int k0=0; k0<512; k0+=32){
          f16x8 bfr = *(const f16x8*)(bp + k0);
#pragma unroll
          for (int ff=0; ff<2; ff++){
            int f = half*2 + ff;
            f16x8 afr = *(const f16x8*)&sm.b.ctx[f*16 + l16][k0 + quad*8];
            acc[ff] = __builtin_amdgcn_mfma_f32_16x16x32_f16(afr, bfr, acc[ff], 0,0,0);
          }
        }
#pragma unroll
        for (int ff=0; ff<2; ff++)
#pragma unroll
          for (int r=0; r<4; r++)
            sm.b.g[wrow][(half*2+ff)*16 + quad*4 + r][l16] = acc[ff][r];
      }
      __syncthreads();
      // cell (verified r7): 64 b x 16 hl / 512 thr = 2 iters
#pragma unroll
      for (int it=0; it<2; ++it){
        int flat = tid + it*512;
        int b2 = flat >> 4, hl = flat & 15;
        int w = hl >> 2, rb = (hl & 3) * 4;
        int hd = j2*16 + hl;
        float4 gp = *(const float4*)(gpart + ((size_t)b2 << 11) + (size_t)hd*4);
        float gi = sm.b.g[w][b2][rb+0] + gp.x;
        float gf = sm.b.g[w][b2][rb+1] + gp.y;
        float gg = sm.b.g[w][b2][rb+2] + gp.z;
        float go = sm.b.g[w][b2][rb+3] + gp.w;
        float fi=sigm_f(gi), ff=sigm_f(gf), fg=tanh_f(gg), fo=sigm_f(go);
        size_t ci = ((size_t)b2 << 9) + hd;
        float cn = ff*cbuf[ci] + fi*fg;
        float hn = fo*tanh_f(cn);
        cbuf[ci] = cn;
        hbuf[((size_t)b2 << 9) + hd] = (f16)hn;
        hs[((size_t)(b2*T_ + t)) * 512 + hd] = f2h(hn);
      }
    }

    // ---------- grid barrier 2 ----------
    ++g;
    __threadfence();
    __syncthreads();
    if (bid == 0){
      if (tid >= 1 && tid < NBLK)
        while (__hip_atomic_load(&slots[tid], __ATOMIC_RELAXED, __HIP_MEMORY_SCOPE_AGENT) < g)
          __builtin_amdgcn_s_sleep(1);
      __syncthreads();
      if (tid == 0) __hip_atomic_store(gen, g, __ATOMIC_RELAXED, __HIP_MEMORY_SCOPE_AGENT);
    } else {
      if (tid == 0){
        __hip_atomic_store(&slots[bid], g, __ATOMIC_RELAXED, __HIP_MEMORY_SCOPE_AGENT);
        while (__hip_atomic_load(gen, __ATOMIC_RELAXED, __HIP_MEMORY_SCOPE_AGENT) < g)
          __builtin_amdgcn_s_sleep(1);
      }
      __syncthreads();
    }
    __threadfence();
  }
}

extern "C" void kernel_launch(void* const* d_in, const int* in_sizes, int n_in,
                              void* d_out, int out_size, void* d_ws, size_t ws_size,
                              hipStream_t stream)
{
  const float* src   = (const float*)d_in[0];
  const int*   text  = (const int*)d_in[1];
  const float* embt  = (const float*)d_in[2];
  const float* Wi2h  = (const float*)d_in[3];
  const float* Wh2h  = (const float*)d_in[4];
  const float* bh2h  = (const float*)d_in[5];
  const float* wsc   = (const float*)d_in[6];
  const float* W_ih  = (const float*)d_in[7];
  const float* b_ih  = (const float*)d_in[8];
  const float* W_hh  = (const float*)d_in[9];
  const float* b_hh  = (const float*)d_in[10];
  const float* Wgen  = (const float*)d_in[11];
  const float* bgen  = (const float*)d_in[12];
  float* out = (float*)d_out;

  // Workspace (~70 MB)
  char* p = (char*)d_ws;
  u16*   sfw    = (u16*)p;    p += (size_t)B_*L_*H_*2;        // 25.2 MB
  u16*   hsw    = (u16*)p;    p += (size_t)B_*T_*H_*2;        //  8.3 MB
  f16*   src16  = (f16*)p;    p += (size_t)B_*L_*CS*2;        // 25.2 MB
  u32*   WhQ    = (u32*)p;    p += (size_t)64*512*4*4;        //  0.5 MB
  f16*   Wi2h16 = (f16*)p;    p += (size_t)H_*CS*2;           //  0.5 MB
  f16*   Wcp    = (f16*)p;    p += (size_t)2048*512*2;        //  2.0 MB
  f16*   WgP    = (f16*)p;    p += (size_t)2048*768*2;        //  3.0 MB
  f16*   Wgen16 = (f16*)p;    p += (size_t)256*512*2;         //  0.25 MB
  f16*   embseq = (f16*)p;    p += (size_t)B_*T_*E_*2;        //  4.2 MB
  f16*   hbuf   = (f16*)p;    p += (size_t)B_*H_*2;           //   64 KB
  float* ctxp   = (float*)p;  p += (size_t)2*B_*512*4;        //  256 KB
  float* denp   = (float*)p;  p += (size_t)128*4;             //  0.5 KB
  float* gpart  = (float*)p;  p += (size_t)B_*2048*4;         //  512 KB
  float* cbuf   = (float*)p;  p += (size_t)B_*H_*4;           //  128 KB
  float* bias_g = (float*)p;  p += (size_t)2048*4;            //    8 KB
  u32*   slots  = (u32*)p;    p += (size_t)256*4;             //    1 KB
  u32*   genw   = (u32*)p;    p += (size_t)64*4;              //  256 B

  hipMemsetAsync(hbuf,   0, (size_t)B_*H_*2, stream);
  hipMemsetAsync(cbuf,   0, (size_t)B_*H_*4, stream);
  hipMemsetAsync(Wgen16, 0, (size_t)256*512*2, stream);
  hipMemsetAsync(slots,  0, (size_t)(256+64)*4, stream);      // slots + gen

  // one-time conversions / packing
  k_cvt     <<<(H_*CS+255)/256,    256, 0, stream>>>(Wi2h, Wi2h16, H_*CS);
  k_cvt     <<<(B_*L_*CS+255)/256, 256, 0, stream>>>(src, src16, B_*L_*CS);
  k_cvt     <<<(NC*512+255)/256,   256, 0, stream>>>(Wgen, (f16*)Wgen16, NC*512);
  k_packwhq <<<(64*512*4+255)/256, 256, 0, stream>>>(Wh2h, WhQ);
  k_packwcp <<<(2048*512+255)/256, 256, 0, stream>>>(W_ih, Wcp);
  k_packwgp2<<<(2048*768+255)/256, 256, 0, stream>>>(W_ih, W_hh, b_ih, b_hh, WgP, bias_g);
  k_emb     <<<(B_*T_*E_+255)/256, 256, 0, stream>>>(text, embt, embseq);

  // sf = src @ Wi2h^T  (MFMA f16)
  k_sf_mfma<<<dim3(384,2), 256, 0, stream>>>(src, Wi2h16, sfw, 512);

  // persistent decode loop (cooperative residency guarantee; custom store-based barrier)
  const u32* whq_a = WhQ; const u16* sf_a = sfw; const f16* src_a = src16;
  const f16* wgp_a = WgP; const f16* wcp_a = Wcp; const f16* emb_a = embseq;
  void* ka[] = {
    (void*)&whq_a, (void*)&sf_a, (void*)&src_a, (void*)&bh2h, (void*)&wsc,
    (void*)&wgp_a, (void*)&bias_g, (void*)&wcp_a, (void*)&emb_a,
    (void*)&hbuf, (void*)&ctxp, (void*)&denp, (void*)&gpart, (void*)&cbuf,
    (void*)&hsw, (void*)&slots, (void*)&genw
  };
  hipLaunchCooperativeKernel(reinterpret_cast<void*>(k_loop),
                             dim3(NBLK), dim3(512), ka, 0, stream);

  // probs = hs @ Wgen^T + bgen (MFMA)
  k_probs_mfma<<<127, 256, 0, stream>>>(hsw, Wgen16, bgen, out);
}

// Round 9
// 6117.274 us; speedup vs baseline: 2.6142x; 2.6142x over previous
//
#include <hip/hip_runtime.h>

typedef unsigned short u16;
typedef unsigned int   u32;
typedef _Float16 f16;
typedef f16   f16x2 __attribute__((ext_vector_type(2)));
typedef f16   f16x8 __attribute__((ext_vector_type(8)));
typedef float f32x4 __attribute__((ext_vector_type(4)));
typedef u32   u32x4 __attribute__((ext_vector_type(4)));

#define B_  64
#define L_  384
#define CS  512   // SRC_DIM
#define H_  512
#define E_  256
#define NC  250
#define T_  127
#define MSHIFT 20.0f   // fixed softmax shift; |logit| <= ||wscore||_1 ~ 20.4 << 88

__device__ __forceinline__ float h2f(u16 u){ f16 h; __builtin_memcpy(&h,&u,2); return (float)h; }
__device__ __forceinline__ u16  f2h(float f){ f16 h=(f16)f; u16 u; __builtin_memcpy(&u,&h,2); return u; }
__device__ __forceinline__ float wredsum(float v){
#pragma unroll
  for (int o=32;o>0;o>>=1) v += __shfl_down(v, o, 64);
  return v;
}
__device__ __forceinline__ float tanh_f(float x){
  x = fminf(fmaxf(x, -15.f), 15.f);
  float e = __expf(2.f*x);
  return (e-1.f)/(e+1.f);
}
__device__ __forceinline__ float sigm_f(float x){
  x = fminf(fmaxf(x, -30.f), 30.f);
  return 1.f/(1.f+__expf(-x));
}
__device__ __forceinline__ float dot2f(u32 a, u32 b, float c){
  f16x2 x, y; __builtin_memcpy(&x,&a,4); __builtin_memcpy(&y,&b,4);
#if __has_builtin(__builtin_amdgcn_fdot2)
  return __builtin_amdgcn_fdot2(x, y, c, false);
#else
  return c + (float)x[0]*(float)y[0] + (float)x[1]*(float)y[1];
#endif
}

// ---------------- one-time converters / packers (all verified in prior rounds) -------------
__global__ __launch_bounds__(256) void k_cvt(const float* __restrict__ in, f16* __restrict__ o, int n){
  int i = blockIdx.x*256 + threadIdx.x;
  if (i < n) o[i] = (f16)in[i];
}

// Quad-k-pair-packed Wh2h (verified r4)
__global__ __launch_bounds__(256) void k_packwhq(const float* __restrict__ Wh, u32* __restrict__ Wq){
  int i = blockIdx.x*256 + threadIdx.x;   // over 64*512*4
  if (i < 64*512*4){
    int kq = i >> 11, n = (i >> 2) & 511, e = i & 3;
    int k = kq*8 + e*2;
    u32 lo = f2h(Wh[(size_t)n*512 + k]);
    u32 hi = f2h(Wh[(size_t)n*512 + k + 1]);
    Wq[i] = lo | (hi<<16);
  }
}

// ctx-part gates weights (verified r5-r7): row pc = hd*4+g <-> orig r = g*512+hd; k in [0,512)
__global__ __launch_bounds__(256) void k_packwcp(const float* __restrict__ Wih, f16* __restrict__ Wcp){
  int i = blockIdx.x*256 + threadIdx.x;   // over 2048*512
  if (i < 2048*512){
    int pc = i >> 9, k = i & 511;
    int r = (pc&3)*512 + (pc>>2);
    Wcp[i] = (f16)Wih[(size_t)r*768 + k];
  }
}

// [emb|h]-part gates weights (verified r5-r7). WgP[pc][k'] with r=(pc&3)*512+(pc>>2).
__global__ __launch_bounds__(256) void k_packwgp2(const float* __restrict__ Wih,
    const float* __restrict__ Whh, const float* __restrict__ bih, const float* __restrict__ bhh,
    f16* __restrict__ WgP, float* __restrict__ bias_g){
  int i = blockIdx.x*256 + threadIdx.x;   // over 2048*768
  if (i < 2048*768){
    int pc = i / 768, k = i - pc*768;
    int r = (pc&3)*512 + (pc>>2);
    float v = (k < 256) ? Wih[(size_t)r*768 + 512 + k] : Whh[(size_t)r*512 + (k-256)];
    WgP[i] = (f16)v;
    if (k == 0) bias_g[pc] = bih[r] + bhh[r];
  }
}

__global__ __launch_bounds__(256) void k_emb(const int* __restrict__ text,
    const float* __restrict__ embt, f16* __restrict__ embseq){
  int i = blockIdx.x*256 + threadIdx.x;
  if (i < B_*T_*E_){
    int bt = i >> 8, col = i & 255;
    int tok = text[bt];
    embseq[i] = (f16)embt[(size_t)tok*E_ + col];
  }
}

// ---------------- GEMM1 (MFMA, verified): C = A(f32)[M,512] @ Wn(f16)[N,512]^T -> f16[M,N]
__global__ __launch_bounds__(256) void k_sf_mfma(
    const float* __restrict__ A, const f16* __restrict__ Wn, u16* __restrict__ Cd, int N)
{
  int w = threadIdx.x >> 6, lane = threadIdx.x & 63;
  int quad = lane >> 4, l16 = lane & 15;
  int m0 = blockIdx.x * 64;
  int nb = blockIdx.y * 256 + w * 64;
  const float* ap0 = A  + (size_t)(m0 + l16)*512 + quad*8;
  const f16*   bp0 = Wn + (size_t)(nb + l16)*512 + quad*8;
  f32x4 acc[4][4] = {};
  for (int k0=0; k0<512; k0+=32){
    f16x8 bfr[4];
#pragma unroll
    for (int nt=0; nt<4; nt++)
      bfr[nt] = *(const f16x8*)(bp0 + (size_t)nt*16*512 + k0);
#pragma unroll
    for (int f=0; f<4; f++){
      const float* ap = ap0 + (size_t)f*16*512 + k0;
      float4 a0 = *(const float4*)ap;
      float4 a1 = *(const float4*)(ap+4);
      f16x8 afr = { (f16)a0.x,(f16)a0.y,(f16)a0.z,(f16)a0.w,
                    (f16)a1.x,(f16)a1.y,(f16)a1.z,(f16)a1.w };
#pragma unroll
      for (int nt=0; nt<4; nt++)
        acc[f][nt] = __builtin_amdgcn_mfma_f32_16x16x32_f16(afr, bfr[nt], acc[f][nt], 0,0,0);
    }
  }
#pragma unroll
  for (int f=0; f<4; f++)
#pragma unroll
    for (int nt=0; nt<4; nt++)
#pragma unroll
      for (int r=0; r<4; r++){
        int m = m0 + f*16 + quad*4 + r;
        int n = nb + nt*16 + l16;
        Cd[(size_t)m*N + n] = f2h(acc[f][nt][r]);
      }
}

// ---------------- probs GEMM (MFMA, verified r6/r7)
__global__ __launch_bounds__(256) void k_probs_mfma(
    const u16* __restrict__ A, const f16* __restrict__ Wn,
    const float* __restrict__ bias, float* __restrict__ Cd)
{
  int w = threadIdx.x >> 6, lane = threadIdx.x & 63;
  int quad = lane >> 4, l16 = lane & 15;
  int m0 = blockIdx.x * 64;
  int nb = w * 64;
  const f16* ap0 = (const f16*)A + (size_t)(m0 + l16)*512 + quad*8;
  const f16* bp0 = Wn + (size_t)(nb + l16)*512 + quad*8;
  f32x4 acc[4][4] = {};
  for (int k0=0; k0<512; k0+=32){
    f16x8 bfr[4];
#pragma unroll
    for (int nt=0; nt<4; nt++)
      bfr[nt] = *(const f16x8*)(bp0 + (size_t)nt*16*512 + k0);
#pragma unroll
    for (int f=0; f<4; f++){
      f16x8 afr = *(const f16x8*)(ap0 + (size_t)f*16*512 + k0);
#pragma unroll
      for (int nt=0; nt<4; nt++)
        acc[f][nt] = __builtin_amdgcn_mfma_f32_16x16x32_f16(afr, bfr[nt], acc[f][nt], 0,0,0);
    }
  }
#pragma unroll
  for (int f=0; f<4; f++)
#pragma unroll
    for (int nt=0; nt<4; nt++)
#pragma unroll
      for (int r=0; r<4; r++){
        int m = m0 + f*16 + quad*4 + r;
        int n = nb + nt*16 + l16;
        if (n < NC) Cd[(size_t)m*NC + n] = acc[f][nt][r] + bias[n];
      }
}

// ---------------- K1: att with atomic ctx/den accumulation. 256 blocks x 512 thr.
// Block (b = bid>>2, q = bid&3): 96 l-rows. Bodies verified r4/r6; partials via atomicAdd.
// q==0 blocks also reset the OTHER ping-pong buffer (consumed by K2 at t-1; stream-ordered).
__global__ __launch_bounds__(512) void k_att2(
    const u32* __restrict__ WhQ, const u16* __restrict__ sf,
    const f16* __restrict__ src16, const f16* __restrict__ hbuf,
    const float* __restrict__ bh2h, const float* __restrict__ wsc,
    float* __restrict__ ctx_cur, float* __restrict__ den_cur,
    float* __restrict__ ctx_other, float* __restrict__ den_other)
{
  const int b = blockIdx.x >> 2;
  const int q = blockIdx.x & 3;
  const int tid = threadIdx.x;
  const int wid = tid >> 6, lane = tid & 63;

  __shared__ __align__(16) u32 sh_h2[256];
  __shared__ float sh_proj[512];
  __shared__ float sh_e[96];
  __shared__ float sh_cp[8][512];

  // reset other ping-pong buffer (safe: K2(t-1) finished before this kernel started)
  if (q == 0){
    ctx_other[(b<<9) + tid] = 0.f;
    if (tid == 0) den_other[b] = 0.f;
  }

  if (tid < 256) sh_h2[tid] = ((const u32*)(hbuf + (size_t)b*512))[tid];
  __syncthreads();
  // proj[n=tid]: 64 iters of u32x4 over WhQ (verified r4)
  {
    const u32* wp = WhQ + ((size_t)tid << 2);
    const u32x4* hp = (const u32x4*)sh_h2;
    float a0=0.f, a1=0.f, a2=0.f, a3=0.f;
#pragma unroll 8
    for (int kq=0; kq<64; kq++){
      u32x4 wq = *(const u32x4*)(wp + ((size_t)kq << 11));
      u32x4 hq = hp[kq];
      a0 = dot2f(wq.x, hq.x, a0);
      a1 = dot2f(wq.y, hq.y, a1);
      a2 = dot2f(wq.z, hq.z, a2);
      a3 = dot2f(wq.w, hq.w, a3);
    }
    sh_proj[tid] = (a0+a1) + (a2+a3) + bh2h[tid];
  }
  __syncthreads();
  // logit rows + fixed-shift exp (verified r4/r6); 8 waves x 12 rows
  {
    float pv[8], wv[8];
#pragma unroll
    for (int j=0;j<8;j++){ pv[j]=sh_proj[lane*8+j]; wv[j]=wsc[lane*8+j]; }
    const int l0 = q*96 + wid*12;
    const f16* sp0 = (const f16*)sf + (((size_t)(b*L_ + l0)) << 9) + lane*8;
#pragma unroll 4
    for (int i=0;i<12;i++){
      f16x8 s = *(const f16x8*)(sp0 + ((size_t)i << 9));
      float v;
      v  = tanh_f((float)s[0]+pv[0])*wv[0];
      v += tanh_f((float)s[1]+pv[1])*wv[1];
      v += tanh_f((float)s[2]+pv[2])*wv[2];
      v += tanh_f((float)s[3]+pv[3])*wv[3];
      v += tanh_f((float)s[4]+pv[4])*wv[4];
      v += tanh_f((float)s[5]+pv[5])*wv[5];
      v += tanh_f((float)s[6]+pv[6])*wv[6];
      v += tanh_f((float)s[7]+pv[7])*wv[7];
      v = wredsum(v);
      if (lane == 0) sh_e[wid*12 + i] = __expf(v - MSHIFT);
    }
  }
  __syncthreads();
  // den partial (wave 0): sum of 96 e's -> atomic
  if (wid == 0){
    float v = sh_e[lane] + (lane < 32 ? sh_e[64+lane] : 0.f);
    v = wredsum(v);
    if (lane == 0) atomicAdd(&den_cur[b], v);
  }
  // partial ctx': wave w rows 12w..12w+11 (coalesced 1KB rows) (verified r6)
  {
    float acc[8] = {0.f,0.f,0.f,0.f,0.f,0.f,0.f,0.f};
    const f16* sp0 = src16 + (((size_t)(b*L_ + q*96 + wid*12)) << 9) + lane*8;
    const float* alp = sh_e + wid*12;
#pragma unroll 4
    for (int i=0;i<12;i++){
      f16x8 v = *(const f16x8*)(sp0 + ((size_t)i << 9));
      float al = alp[i];
#pragma unroll
      for (int e=0;e<8;e++) acc[e] += al*(float)v[e];
    }
#pragma unroll
    for (int e=0;e<8;e++) sh_cp[wid][lane*8+e] = acc[e];
  }
  __syncthreads();
  if (tid < 256){
    int c0 = tid*2;
    float v0 = (((sh_cp[0][c0]+sh_cp[1][c0])+(sh_cp[2][c0]+sh_cp[3][c0]))
              + ((sh_cp[4][c0]+sh_cp[5][c0])+(sh_cp[6][c0]+sh_cp[7][c0])));
    int c1 = c0+1;
    float v1 = (((sh_cp[0][c1]+sh_cp[1][c1])+(sh_cp[2][c1]+sh_cp[3][c1]))
              + ((sh_cp[4][c1]+sh_cp[5][c1])+(sh_cp[6][c1]+sh_cp[7][c1])));
    atomicAdd(&ctx_cur[(b<<9) + c0], v0);
    atomicAdd(&ctx_cur[(b<<9) + c1], v1);
  }
}

// ---------------- K2: normalize ctx -> LDS f16; fused gates MFMA (ctx+emb+h) + LSTM cell.
// 32 blocks x 512 thr; block j2 owns h-dims [16*j2,16*j2+16) = packed pc rows [64*j2,64*j2+64).
__global__ __launch_bounds__(512) void k_cell(
    const float* __restrict__ ctx_cur, const float* __restrict__ den_cur,
    const f16* __restrict__ Wcp, const f16* __restrict__ WgP,
    const float* __restrict__ bias_g, const f16* __restrict__ embseq,
    float* __restrict__ cbuf, f16* __restrict__ hbuf, u16* __restrict__ hs, int t)
{
  __shared__ f16   sh_ctx[64][520];     // 66.5 KB
  __shared__ float sh_g[4][64][17];     // 17.4 KB
  __shared__ float sh_inv[64];
  const int tid = threadIdx.x;
  const int wid = tid >> 6, lane = tid & 63;
  const int quad = lane >> 4, l16 = lane & 15;
  const int j2 = blockIdx.x;            // 0..31

  if (tid < 64) sh_inv[tid] = 1.f/den_cur[tid];
  __syncthreads();

  // normalize summed ctx -> f16 LDS (8192 float4 / 512 thr = 16 iters) [r7-verified pattern]
#pragma unroll 4
  for (int i=0;i<16;i++){
    int flat = tid + i*512;
    int b = flat >> 7, c4 = flat & 127;
    float4 v0 = *(const float4*)(ctx_cur + ((size_t)b << 9) + (c4 << 2));
    float inv = sh_inv[b];
    ushort4 o;
    o.x = f2h(v0.x*inv);
    o.y = f2h(v0.y*inv);
    o.z = f2h(v0.z*inv);
    o.w = f2h(v0.w*inv);
    *(ushort4*)&sh_ctx[b][c4*4] = o;
  }
  __syncthreads();

  // fused gates MFMA: wave (wrow = wid&3, half = wid>>2); B rows pc = j2*64 + wrow*16 + l16.
  // acc accumulates ctx-part (Wcp, LDS A) + emb-part + h-part (WgP, global A) [r6/r7-verified]
  {
    const int wrow = wid & 3, half = wid >> 2;
    const int pc = j2*64 + wrow*16 + l16;
    const f16* bpc = Wcp + (size_t)pc*512 + quad*8;
    const f16* bpg = WgP + (size_t)pc*768 + quad*8;
    f32x4 acc[2] = {};
    for (int k0=0; k0<512; k0+=32){
      f16x8 bfr = *(const f16x8*)(bpc + k0);
#pragma unroll
      for (int ff=0; ff<2; ff++){
        int f = half*2 + ff;
        f16x8 afr = *(const f16x8*)&sh_ctx[f*16 + l16][k0 + quad*8];
        acc[ff] = __builtin_amdgcn_mfma_f32_16x16x32_f16(afr, bfr, acc[ff], 0,0,0);
      }
    }
    for (int k0=0; k0<256; k0+=32){
      f16x8 bfr = *(const f16x8*)(bpg + k0);
#pragma unroll
      for (int ff=0; ff<2; ff++){
        int br = (half*2+ff)*16 + l16;
        f16x8 afr = *(const f16x8*)(embseq + (((size_t)(br*T_ + t)) << 8) + quad*8 + k0);
        acc[ff] = __builtin_amdgcn_mfma_f32_16x16x32_f16(afr, bfr, acc[ff], 0,0,0);
      }
    }
    for (int k0=0; k0<512; k0+=32){
      f16x8 bfr = *(const f16x8*)(bpg + 256 + k0);
#pragma unroll
      for (int ff=0; ff<2; ff++){
        int br = (half*2+ff)*16 + l16;
        f16x8 afr = *(const f16x8*)(hbuf + (size_t)br*512 + quad*8 + k0);
        acc[ff] = __builtin_amdgcn_mfma_f32_16x16x32_f16(afr, bfr, acc[ff], 0,0,0);
      }
    }
#pragma unroll
    for (int ff=0; ff<2; ff++)
#pragma unroll
      for (int r=0; r<4; r++)
        sh_g[wrow][(half*2+ff)*16 + quad*4 + r][l16] = acc[ff][r];
  }
  __syncthreads();

  // cell (verified r7): 64 b x 16 hl / 512 thr = 2 iters; bias via contiguous float4
#pragma unroll
  for (int it=0; it<2; ++it){
    int flat = tid + it*512;
    int b2 = flat >> 4, hl = flat & 15;
    int w = hl >> 2, rb = (hl & 3) * 4;
    int hd = j2*16 + hl;
    float4 bias4 = *(const float4*)(bias_g + (size_t)hd*4);
    float gi = sh_g[w][b2][rb+0] + bias4.x;
    float gf = sh_g[w][b2][rb+1] + bias4.y;
    float gg = sh_g[w][b2][rb+2] + bias4.z;
    float go = sh_g[w][b2][rb+3] + bias4.w;
    float fi=sigm_f(gi), ff=sigm_f(gf), fg=tanh_f(gg), fo=sigm_f(go);
    size_t ci = ((size_t)b2 << 9) + hd;
    float cn = ff*cbuf[ci] + fi*fg;
    float hn = fo*tanh_f(cn);
    cbuf[ci] = cn;
    hbuf[((size_t)b2 << 9) + hd] = (f16)hn;
    hs[((size_t)(b2*T_ + t)) * 512 + hd] = f2h(hn);
  }
}

extern "C" void kernel_launch(void* const* d_in, const int* in_sizes, int n_in,
                              void* d_out, int out_size, void* d_ws, size_t ws_size,
                              hipStream_t stream)
{
  const float* src   = (const float*)d_in[0];
  const int*   text  = (const int*)d_in[1];
  const float* embt  = (const float*)d_in[2];
  const float* Wi2h  = (const float*)d_in[3];
  const float* Wh2h  = (const float*)d_in[4];
  const float* bh2h  = (const float*)d_in[5];
  const float* wsc   = (const float*)d_in[6];
  const float* W_ih  = (const float*)d_in[7];
  const float* b_ih  = (const float*)d_in[8];
  const float* W_hh  = (const float*)d_in[9];
  const float* b_hh  = (const float*)d_in[10];
  const float* Wgen  = (const float*)d_in[11];
  const float* bgen  = (const float*)d_in[12];
  float* out = (float*)d_out;

  // Workspace (~70 MB)
  char* p = (char*)d_ws;
  u16*   sfw    = (u16*)p;    p += (size_t)B_*L_*H_*2;        // 25.2 MB
  u16*   hsw    = (u16*)p;    p += (size_t)B_*T_*H_*2;        //  8.3 MB
  f16*   src16  = (f16*)p;    p += (size_t)B_*L_*CS*2;        // 25.2 MB
  u32*   WhQ    = (u32*)p;    p += (size_t)64*512*4*4;        //  0.5 MB
  f16*   Wi2h16 = (f16*)p;    p += (size_t)H_*CS*2;           //  0.5 MB
  f16*   Wcp    = (f16*)p;    p += (size_t)2048*512*2;        //  2.0 MB
  f16*   WgP    = (f16*)p;    p += (size_t)2048*768*2;        //  3.0 MB
  f16*   Wgen16 = (f16*)p;    p += (size_t)256*512*2;         //  0.25 MB
  f16*   embseq = (f16*)p;    p += (size_t)B_*T_*E_*2;        //  4.2 MB
  f16*   hbuf   = (f16*)p;    p += (size_t)B_*H_*2;           //   64 KB
  float* ctxab  = (float*)p;  p += (size_t)2*B_*512*4;        //  256 KB (ping-pong)
  float* denab  = (float*)p;  p += (size_t)2*64*4;            //  0.5 KB (ping-pong)
  float* cbuf   = (float*)p;  p += (size_t)B_*H_*4;           //  128 KB
  float* bias_g = (float*)p;  p += (size_t)2048*4;            //    8 KB

  hipMemsetAsync(hbuf,   0, (size_t)B_*H_*2, stream);
  hipMemsetAsync(cbuf,   0, (size_t)B_*H_*4, stream);
  hipMemsetAsync(Wgen16, 0, (size_t)256*512*2, stream);
  hipMemsetAsync(ctxab,  0, (size_t)2*B_*512*4, stream);
  hipMemsetAsync(denab,  0, (size_t)2*64*4, stream);

  // one-time conversions / packing
  k_cvt     <<<(H_*CS+255)/256,    256, 0, stream>>>(Wi2h, Wi2h16, H_*CS);
  k_cvt     <<<(B_*L_*CS+255)/256, 256, 0, stream>>>(src, src16, B_*L_*CS);
  k_cvt     <<<(NC*512+255)/256,   256, 0, stream>>>(Wgen, (f16*)Wgen16, NC*512);
  k_packwhq <<<(64*512*4+255)/256, 256, 0, stream>>>(Wh2h, WhQ);
  k_packwcp <<<(2048*512+255)/256, 256, 0, stream>>>(W_ih, Wcp);
  k_packwgp2<<<(2048*768+255)/256, 256, 0, stream>>>(W_ih, W_hh, b_ih, b_hh, WgP, bias_g);
  k_emb     <<<(B_*T_*E_+255)/256, 256, 0, stream>>>(text, embt, embseq);

  // sf = src @ Wi2h^T  (MFMA f16)
  k_sf_mfma<<<dim3(384,2), 256, 0, stream>>>(src, Wi2h16, sfw, 512);

  // decode loop: 2 kernels per step, ping-pong atomic ctx/den buffers
  for (int t=0; t<T_; t++){
    float* ctx_cur   = ctxab + (size_t)(t & 1)*B_*512;
    float* ctx_other = ctxab + (size_t)((t & 1) ^ 1)*B_*512;
    float* den_cur   = denab + (size_t)(t & 1)*64;
    float* den_other = denab + (size_t)((t & 1) ^ 1)*64;
    k_att2<<<256, 512, 0, stream>>>(WhQ, sfw, src16, hbuf, bh2h, wsc,
                                    ctx_cur, den_cur, ctx_other, den_other);
    k_cell<<<32, 512, 0, stream>>>(ctx_cur, den_cur, Wcp, WgP, bias_g, embseq,
                                   cbuf, hbuf, hsw, t);
  }

  // probs = hs @ Wgen^T + bgen (MFMA)
  k_probs_mfma<<<127, 256, 0, stream>>>(hsw, Wgen16, bgen, out);
}